// Round 1
// baseline (87.219 us; speedup 1.0000x reference)
//
#include <hip/hip_runtime.h>

// Problem constants
#define B_   64
#define L_   1024
#define D_   1280   // 320 float4
#define H1_  640
#define H2_  320
#define NSPLIT 8    // l-stripes for pooling
#define KS_  16     // k-splits for mlp1
#define KC_  80     // 1280/16

// ---------------- Kernel 1: masked partial sums over l-stripes ----------------
__global__ void pool_partial(const float* __restrict__ rep, const int* __restrict__ blen,
                             float* __restrict__ part) {
    const int s   = blockIdx.x;     // stripe 0..7
    const int b   = blockIdx.y;     // batch
    const int tid = threadIdx.x;    // 0..319 (float4 lane)
    const int len = blen[b];

    int l0 = s * (L_ / NSPLIT);
    int l1 = l0 + (L_ / NSPLIT);
    if (l0 < 1) l0 = 1;
    const int hi = len - 1;         // exclusive upper bound
    if (l1 > hi) l1 = hi;

    float4 acc = make_float4(0.f, 0.f, 0.f, 0.f);
    const float4* base = (const float4*)rep + (size_t)b * L_ * (D_ / 4);
    #pragma unroll 4
    for (int l = l0; l < l1; ++l) {
        float4 v = base[(size_t)l * (D_ / 4) + tid];
        acc.x += v.x; acc.y += v.y; acc.z += v.z; acc.w += v.w;
    }
    // always write (ws is poisoned; empty stripes must contribute zeros)
    float4* p = (float4*)part + ((size_t)s * B_ + b) * (D_ / 4);
    p[tid] = acc;
}

// ---------------- Kernel 2: reduce stripes, divide by count ----------------
__global__ void pool_reduce(const float* __restrict__ part, const int* __restrict__ blen,
                            float* __restrict__ pooled) {
    const int b   = blockIdx.x;
    const int tid = threadIdx.x;    // 0..319
    float4 acc = make_float4(0.f, 0.f, 0.f, 0.f);
    #pragma unroll
    for (int s = 0; s < NSPLIT; ++s) {
        float4 v = ((const float4*)part)[((size_t)s * B_ + b) * (D_ / 4) + tid];
        acc.x += v.x; acc.y += v.y; acc.z += v.z; acc.w += v.w;
    }
    int cnt = blen[b] - 2;
    if (cnt < 1) cnt = 1;
    const float inv = 1.0f / (float)cnt;
    acc.x *= inv; acc.y *= inv; acc.z *= inv; acc.w *= inv;
    ((float4*)pooled)[(size_t)b * (D_ / 4) + tid] = acc;
}

// ---------------- Kernel 3: h-partials = pooled @ W1 (k-split) ----------------
// grid (5 j-tiles of 128, 16 k-splits of 80), block 256.
// Thread owns 16 batches x 2 columns. W1 read exactly once grid-wide.
__global__ void mlp1_partial(const float* __restrict__ pooled, const float* __restrict__ W1,
                             float* __restrict__ hpart) {
    const int jt  = blockIdx.x;     // 0..4
    const int ks  = blockIdx.y;     // 0..15
    const int tid = threadIdx.x;    // 0..255
    const int jl  = tid & 63;
    const int b0  = (tid >> 6) * 16;
    const int k0  = ks * KC_;
    const int j0  = jt * 128;

    __shared__ float pl[B_][KC_];   // pooled tile [b][kk]
    for (int e = tid; e < B_ * KC_; e += 256) {
        int b = e / KC_, kk = e % KC_;
        pl[b][kk] = pooled[(size_t)b * D_ + k0 + kk];
    }
    __syncthreads();

    float acc0[16], acc1[16];
    #pragma unroll
    for (int r = 0; r < 16; ++r) { acc0[r] = 0.f; acc1[r] = 0.f; }

    const float* w1p = W1 + (size_t)k0 * H1_ + j0 + jl;
    for (int kk = 0; kk < KC_; kk += 4) {
        const float w00 = w1p[(size_t)(kk + 0) * H1_];
        const float w01 = w1p[(size_t)(kk + 1) * H1_];
        const float w02 = w1p[(size_t)(kk + 2) * H1_];
        const float w03 = w1p[(size_t)(kk + 3) * H1_];
        const float w10 = w1p[(size_t)(kk + 0) * H1_ + 64];
        const float w11 = w1p[(size_t)(kk + 1) * H1_ + 64];
        const float w12 = w1p[(size_t)(kk + 2) * H1_ + 64];
        const float w13 = w1p[(size_t)(kk + 3) * H1_ + 64];
        #pragma unroll
        for (int r = 0; r < 16; ++r) {
            float4 p = *(const float4*)&pl[b0 + r][kk];
            acc0[r] = fmaf(p.x, w00, acc0[r]);
            acc0[r] = fmaf(p.y, w01, acc0[r]);
            acc0[r] = fmaf(p.z, w02, acc0[r]);
            acc0[r] = fmaf(p.w, w03, acc0[r]);
            acc1[r] = fmaf(p.x, w10, acc1[r]);
            acc1[r] = fmaf(p.y, w11, acc1[r]);
            acc1[r] = fmaf(p.z, w12, acc1[r]);
            acc1[r] = fmaf(p.w, w13, acc1[r]);
        }
    }

    float* hp = hpart + (size_t)ks * B_ * H1_;
    #pragma unroll
    for (int r = 0; r < 16; ++r) {
        hp[(size_t)(b0 + r) * H1_ + j0 + jl]      = acc0[r];
        hp[(size_t)(b0 + r) * H1_ + j0 + 64 + jl] = acc1[r];
    }
}

// ---------------- Kernel 4: h reduce + relu, emb, y ----------------
// block per batch, 320 threads.
__global__ void mlp23(const float* __restrict__ hpart, const float* __restrict__ b1,
                      const float* __restrict__ W2, const float* __restrict__ b2,
                      const float* __restrict__ W3, const float* __restrict__ b3,
                      float* __restrict__ out) {
    const int b   = blockIdx.x;
    const int tid = threadIdx.x;   // 0..319
    __shared__ float hrow[H1_];
    __shared__ float erow[H2_];

    // phase 1: h[b][j] = relu(sum_ks hpart + b1)
    for (int j = tid; j < H1_; j += 320) {
        float s = b1[j];
        #pragma unroll
        for (int ks = 0; ks < KS_; ++ks)
            s += hpart[((size_t)ks * B_ + b) * H1_ + j];
        hrow[j] = fmaxf(s, 0.f);
    }
    __syncthreads();

    // phase 2: emb[b][j] = relu(hrow . W2[:,j] + b2[j])
    {
        const int j = tid;
        float s = b2[j];
        #pragma unroll 8
        for (int k = 0; k < H1_; ++k)
            s = fmaf(hrow[k], W2[(size_t)k * H2_ + j], s);
        s = fmaxf(s, 0.f);
        erow[j] = s;
        out[128 + (size_t)b * H2_ + j] = s;
    }
    __syncthreads();

    // phase 3: y[b][o] = erow . W3[:,o] + b3[o]   (two waves, shuffle reduce)
    if (tid < 128) {
        const int o = tid >> 6, lane = tid & 63;
        float s = 0.f;
        for (int j = lane; j < H2_; j += 64)
            s = fmaf(erow[j], W3[(size_t)j * 2 + o], s);
        #pragma unroll
        for (int off = 32; off >= 1; off >>= 1)
            s += __shfl_down(s, off, 64);
        if (lane == 0) out[(size_t)b * 2 + o] = s + b3[o];
    }
}

extern "C" void kernel_launch(void* const* d_in, const int* in_sizes, int n_in,
                              void* d_out, int out_size, void* d_ws, size_t ws_size,
                              hipStream_t stream) {
    const float* rep  = (const float*)d_in[0];
    const int*   blen = (const int*)  d_in[1];
    const float* W1   = (const float*)d_in[2];
    const float* b1   = (const float*)d_in[3];
    const float* W2   = (const float*)d_in[4];
    const float* b2   = (const float*)d_in[5];
    const float* W3   = (const float*)d_in[6];
    const float* b3   = (const float*)d_in[7];
    float* out = (float*)d_out;

    // workspace layout (floats)
    float* ws     = (float*)d_ws;
    float* part   = ws;                                   // 8*64*1280   = 655360
    float* pooled = part + (size_t)NSPLIT * B_ * D_;      // 64*1280    = 81920
    float* hpart  = pooled + (size_t)B_ * D_;             // 16*64*640  = 655360

    pool_partial<<<dim3(NSPLIT, B_), 320, 0, stream>>>(rep, blen, part);
    pool_reduce <<<B_, 320, 0, stream>>>(part, blen, pooled);
    mlp1_partial<<<dim3(5, KS_), 256, 0, stream>>>(pooled, W1, hpart);
    mlp23       <<<B_, 320, 0, stream>>>(hpart, b1, W2, b2, W3, b3, out);
}

// Round 2
// 77.532 us; speedup vs baseline: 1.1249x; 1.1249x over previous
//
#include <hip/hip_runtime.h>

// Problem constants
#define B_   64
#define L_   1024
#define D_   1280   // 320 float4
#define H1_  640
#define H2_  320
#define NSPLIT 16   // stripes per batch for pooling (even split of valid rows)
#define KS_  16     // k-splits for mlp1
#define KC_  80     // 1280/16

// ---------------- Kernel 1: masked partial sums, even-split stripes ----------------
// Each batch's valid range [1, len-1) is split evenly into NSPLIT stripes, so
// every block has work proportional to len/NSPLIT (<= 64 rows) — no idle blocks.
__global__ void pool_partial(const float* __restrict__ rep, const int* __restrict__ blen,
                             float* __restrict__ part) {
    const int s   = blockIdx.x;     // stripe 0..NSPLIT-1
    const int b   = blockIdx.y;     // batch
    const int tid = threadIdx.x;    // 0..319 (float4 lane)
    const int len = blen[b];
    const int n   = len - 2;        // valid rows (>=1 guaranteed)

    const int l0 = 1 + (s * n) / NSPLIT;
    const int l1 = 1 + ((s + 1) * n) / NSPLIT;

    float4 acc = make_float4(0.f, 0.f, 0.f, 0.f);
    const float4* base = (const float4*)rep + (size_t)b * L_ * (D_ / 4);
    #pragma unroll 4
    for (int l = l0; l < l1; ++l) {
        float4 v = base[(size_t)l * (D_ / 4) + tid];
        acc.x += v.x; acc.y += v.y; acc.z += v.z; acc.w += v.w;
    }
    // always write (ws is poisoned; empty stripes must contribute zeros)
    float4* p = (float4*)part + ((size_t)s * B_ + b) * (D_ / 4);
    p[tid] = acc;
}

// ---------------- Kernel 2: reduce stripes, divide by count ----------------
__global__ void pool_reduce(const float* __restrict__ part, const int* __restrict__ blen,
                            float* __restrict__ pooled) {
    const int b   = blockIdx.x;
    const int tid = threadIdx.x;    // 0..319
    float4 acc = make_float4(0.f, 0.f, 0.f, 0.f);
    #pragma unroll
    for (int s = 0; s < NSPLIT; ++s) {
        float4 v = ((const float4*)part)[((size_t)s * B_ + b) * (D_ / 4) + tid];
        acc.x += v.x; acc.y += v.y; acc.z += v.z; acc.w += v.w;
    }
    int cnt = blen[b] - 2;
    if (cnt < 1) cnt = 1;
    const float inv = 1.0f / (float)cnt;
    acc.x *= inv; acc.y *= inv; acc.z *= inv; acc.w *= inv;
    ((float4*)pooled)[(size_t)b * (D_ / 4) + tid] = acc;
}

// ---------------- Kernel 3: h-partials = pooled @ W1 (k-split) ----------------
// grid (5 j-tiles of 128, 16 k-splits of 80), block 256.
// Thread owns 16 batches x 2 columns. W1 read exactly once grid-wide.
__global__ void mlp1_partial(const float* __restrict__ pooled, const float* __restrict__ W1,
                             float* __restrict__ hpart) {
    const int jt  = blockIdx.x;     // 0..4
    const int ks  = blockIdx.y;     // 0..15
    const int tid = threadIdx.x;    // 0..255
    const int jl  = tid & 63;
    const int b0  = (tid >> 6) * 16;
    const int k0  = ks * KC_;
    const int j0  = jt * 128;

    __shared__ float pl[B_][KC_];   // pooled tile [b][kk]
    for (int e = tid; e < B_ * KC_; e += 256) {
        int b = e / KC_, kk = e % KC_;
        pl[b][kk] = pooled[(size_t)b * D_ + k0 + kk];
    }
    __syncthreads();

    float acc0[16], acc1[16];
    #pragma unroll
    for (int r = 0; r < 16; ++r) { acc0[r] = 0.f; acc1[r] = 0.f; }

    const float* w1p = W1 + (size_t)k0 * H1_ + j0 + jl;
    for (int kk = 0; kk < KC_; kk += 4) {
        const float w00 = w1p[(size_t)(kk + 0) * H1_];
        const float w01 = w1p[(size_t)(kk + 1) * H1_];
        const float w02 = w1p[(size_t)(kk + 2) * H1_];
        const float w03 = w1p[(size_t)(kk + 3) * H1_];
        const float w10 = w1p[(size_t)(kk + 0) * H1_ + 64];
        const float w11 = w1p[(size_t)(kk + 1) * H1_ + 64];
        const float w12 = w1p[(size_t)(kk + 2) * H1_ + 64];
        const float w13 = w1p[(size_t)(kk + 3) * H1_ + 64];
        #pragma unroll
        for (int r = 0; r < 16; ++r) {
            float4 p = *(const float4*)&pl[b0 + r][kk];
            acc0[r] = fmaf(p.x, w00, acc0[r]);
            acc0[r] = fmaf(p.y, w01, acc0[r]);
            acc0[r] = fmaf(p.z, w02, acc0[r]);
            acc0[r] = fmaf(p.w, w03, acc0[r]);
            acc1[r] = fmaf(p.x, w10, acc1[r]);
            acc1[r] = fmaf(p.y, w11, acc1[r]);
            acc1[r] = fmaf(p.z, w12, acc1[r]);
            acc1[r] = fmaf(p.w, w13, acc1[r]);
        }
    }

    float* hp = hpart + (size_t)ks * B_ * H1_;
    #pragma unroll
    for (int r = 0; r < 16; ++r) {
        hp[(size_t)(b0 + r) * H1_ + j0 + jl]      = acc0[r];
        hp[(size_t)(b0 + r) * H1_ + j0 + 64 + jl] = acc1[r];
    }
}

// ---------------- Kernel 4: h reduce + relu, emb, y ----------------
// block per batch, 320 threads.
__global__ void mlp23(const float* __restrict__ hpart, const float* __restrict__ b1,
                      const float* __restrict__ W2, const float* __restrict__ b2,
                      const float* __restrict__ W3, const float* __restrict__ b3,
                      float* __restrict__ out) {
    const int b   = blockIdx.x;
    const int tid = threadIdx.x;   // 0..319
    __shared__ float hrow[H1_];
    __shared__ float erow[H2_];

    // phase 1: h[b][j] = relu(sum_ks hpart + b1)
    for (int j = tid; j < H1_; j += 320) {
        float s = b1[j];
        #pragma unroll
        for (int ks = 0; ks < KS_; ++ks)
            s += hpart[((size_t)ks * B_ + b) * H1_ + j];
        hrow[j] = fmaxf(s, 0.f);
    }
    __syncthreads();

    // phase 2: emb[b][j] = relu(hrow . W2[:,j] + b2[j])
    {
        const int j = tid;
        float s = b2[j];
        #pragma unroll 8
        for (int k = 0; k < H1_; ++k)
            s = fmaf(hrow[k], W2[(size_t)k * H2_ + j], s);
        s = fmaxf(s, 0.f);
        erow[j] = s;
        out[128 + (size_t)b * H2_ + j] = s;
    }
    __syncthreads();

    // phase 3: y[b][o] = erow . W3[:,o] + b3[o]   (two waves, shuffle reduce)
    if (tid < 128) {
        const int o = tid >> 6, lane = tid & 63;
        float s = 0.f;
        for (int j = lane; j < H2_; j += 64)
            s = fmaf(erow[j], W3[(size_t)j * 2 + o], s);
        #pragma unroll
        for (int off = 32; off >= 1; off >>= 1)
            s += __shfl_down(s, off, 64);
        if (lane == 0) out[(size_t)b * 2 + o] = s + b3[o];
    }
}

extern "C" void kernel_launch(void* const* d_in, const int* in_sizes, int n_in,
                              void* d_out, int out_size, void* d_ws, size_t ws_size,
                              hipStream_t stream) {
    const float* rep  = (const float*)d_in[0];
    const int*   blen = (const int*)  d_in[1];
    const float* W1   = (const float*)d_in[2];
    const float* b1   = (const float*)d_in[3];
    const float* W2   = (const float*)d_in[4];
    const float* b2   = (const float*)d_in[5];
    const float* W3   = (const float*)d_in[6];
    const float* b3   = (const float*)d_in[7];
    float* out = (float*)d_out;

    // workspace layout (floats): part 16*64*1280 + pooled 64*1280 + hpart 16*64*640
    float* ws     = (float*)d_ws;
    float* part   = ws;
    float* pooled = part + (size_t)NSPLIT * B_ * D_;
    float* hpart  = pooled + (size_t)B_ * D_;

    pool_partial<<<dim3(NSPLIT, B_), 320, 0, stream>>>(rep, blen, part);
    pool_reduce <<<B_, 320, 0, stream>>>(part, blen, pooled);
    mlp1_partial<<<dim3(5, KS_), 256, 0, stream>>>(pooled, W1, hpart);
    mlp23       <<<B_, 320, 0, stream>>>(hpart, b1, W2, b2, W3, b3, out);
}